// Round 3
// baseline (113.801 us; speedup 1.0000x reference)
//
#include <hip/hip_runtime.h>

#define VV   50257
#define EE   512
#define HH   1024
#define TT   512
#define SS   8
#define TSS  128
#define MOOV 20

// ws layout (floats)
#define OFF_Q      0        // 1024
#define OFF_COMB   1024     // 3584 : [emb(512) | c_enc(1024) | c_name(1024) | c_type(1024)]
#define OFF_SENC   4608     // 512
#define OFF_SNAME  5120     // 1024
#define OFF_STYPE  6144     // 1024
#define OFF_X      7168     // 512
#define OFF_GATES  7680     // 4096
#define OFF_H1     11776    // 1024
#define OFF_C1     12800    // 1024
#define OFF_GENP   13824    // 1
#define OFF_SUMEXP 13825    // 1
#define OFF_SIM    13832    // 8
#define OFF_QC     13840    // 1024
#define OFF_ATTN   14864    // 1024
#define OFF_LOGIT  15888    // 50257 (stores exp(logit))
#define OFF_PCOPY  66148    // 50277 (scaled copy probs, zeroed each call)

__device__ __forceinline__ float dot4(float4 a, float4 b) {
    return a.x*b.x + a.y*b.y + a.z*b.z + a.w*b.w;
}
__device__ __forceinline__ float wred(float v) {
    #pragma unroll
    for (int o = 32; o; o >>= 1) v += __shfl_down(v, o, 64);
    return v;
}
__device__ __forceinline__ float wred_all(float v) {
    #pragma unroll
    for (int o = 32; o; o >>= 1) v += __shfl_xor(v, o, 64);
    return v;
}
__device__ __forceinline__ float wmax_all(float v) {
    #pragma unroll
    for (int o = 32; o; o >>= 1) v = fmaxf(v, __shfl_xor(v, o, 64));
    return v;
}

// R rows per wave, CH float4-chunks per lane per row; vector held in registers.
// All R*CH loads are issued before any use -> R*CH KB in flight per wave.
template<int R, int CH>
__device__ __forceinline__ void rowsN_dot(const float* __restrict__ W, int ld,
                                          int row0, int rowmax,
                                          const float4 vec[CH], int lane, float s[R]) {
    float4 w[R][CH];
    #pragma unroll
    for (int r = 0; r < R; ++r) {
        int row = row0 + r; if (row > rowmax) row = rowmax;
        const float4* Wr = (const float4*)(W + (size_t)row * ld);
        #pragma unroll
        for (int k = 0; k < CH; ++k) w[r][k] = Wr[lane + 64 * k];
    }
    #pragma unroll
    for (int r = 0; r < R; ++r) {
        float acc = 0.f;
        #pragma unroll
        for (int k = 0; k < CH; ++k) acc += dot4(w[r][k], vec[k]);
        s[r] = acc;
    }
}

// K1: zero scratch (comb acc, sumexp, pcopy), copy emb, q = W_ma_attn @ emb + b
__global__ void k_init_q(const float* __restrict__ emb, const float* __restrict__ W,
                         const float* __restrict__ bias, float* __restrict__ ws) {
    int tid = threadIdx.x, bid = blockIdx.x;
    int gid = bid * 256 + tid;
    if (gid < 3072) ws[OFF_COMB + 512 + gid] = 0.f;   // c_enc/c_name/c_type accumulators
    if (gid == 3072) ws[OFF_SUMEXP] = 0.f;
    if (gid < 512) ws[OFF_COMB + gid] = emb[gid];
    if (gid < VV + MOOV) ws[OFF_PCOPY + gid] = 0.f;
    if (bid >= 64) return;                             // only first 64 blocks compute q
    int wave = tid >> 6, lane = tid & 63;
    const float4* e4 = (const float4*)emb;
    float4 ev[2] = { e4[lane], e4[lane + 64] };
    int row0 = (bid * 4 + wave) * 4;                   // < 1024
    float s[4];
    rowsN_dot<4, 2>(W, EE, row0, 1023, ev, lane, s);
    #pragma unroll
    for (int r = 0; r < 4; ++r) {
        float v = wred(s[r]);
        if (lane == 0) ws[OFF_Q + row0 + r] = v + bias[row0 + r];
    }
}

// K2: attention scores (enc 512, name 1024, type 1024 rows) + sim (block 160)
__global__ void k_scores(const float* __restrict__ enc, const float* __restrict__ name,
                         const float* __restrict__ type, float* __restrict__ ws) {
    int b = blockIdx.x, tid = threadIdx.x;
    int wave = tid >> 6, lane = tid & 63;
    if (b < 160) {
        const float* src; float* dst; int r0;
        if (b < 32)      { src = enc;  dst = ws + OFF_SENC;  r0 = b * 16 + wave * 4; }
        else if (b < 96) { src = name; dst = ws + OFF_SNAME; r0 = (b - 32) * 16 + wave * 4; }
        else             { src = type; dst = ws + OFF_STYPE; r0 = (b - 96) * 16 + wave * 4; }
        const float4* q4 = (const float4*)(ws + OFF_Q);
        float4 qv[4] = { q4[lane], q4[lane + 64], q4[lane + 128], q4[lane + 192] };
        float s[4];
        rowsN_dot<4, 4>(src, HH, r0, 1 << 30, qv, lane, s);
        #pragma unroll
        for (int r = 0; r < 4; ++r) {
            float v = wred(s[r]);
            if (lane == 0) dst[r0 + r] = v;
        }
    } else {
        // sim = softmax(enc_last @ name_hiddens[:, -1, :].T)
        __shared__ float sd[8];
        const float4* el = (const float4*)(enc + (size_t)(TT - 1) * HH);
        for (int s8 = wave; s8 < 8; s8 += 4) {
            const float4* R = (const float4*)(name + ((size_t)s8 * TSS + (TSS - 1)) * HH);
            float s = 0.f;
            #pragma unroll
            for (int k = 0; k < 4; ++k) s += dot4(R[lane + 64 * k], el[lane + 64 * k]);
            s = wred(s);
            if (lane == 0) sd[s8] = s;
        }
        __syncthreads();
        if (tid == 0) {
            float m = -1e30f;
            for (int i = 0; i < 8; ++i) m = fmaxf(m, sd[i]);
            float e[8], su = 0.f;
            for (int i = 0; i < 8; ++i) { e[i] = expf(sd[i] - m); su += e[i]; }
            for (int i = 0; i < 8; ++i) ws[OFF_SIM + i] = e[i] / su;
        }
    }
}

// K3: context vectors with fused (redundant per-block) softmax over raw scores.
__global__ void k_ctx(const float* __restrict__ enc, const float* __restrict__ name,
                      const float* __restrict__ type, float* __restrict__ ws) {
    int b = blockIdx.x, tid = threadIdx.x;
    const float* src; const float* sc; float* dst; int i, n;
    if (b < 64)       { i = b;       src = enc;  sc = ws + OFF_SENC;  dst = ws + OFF_COMB + 512;  n = 512;  }
    else if (b < 192) { i = b - 64;  src = name; sc = ws + OFF_SNAME; dst = ws + OFF_COMB + 1536; n = 1024; }
    else              { i = b - 192; src = type; sc = ws + OFF_STYPE; dst = ws + OFF_COMB + 2560; n = 1024; }
    __shared__ float red[4];
    __shared__ float sh_m, sh_s;
    float mloc = -1e30f;
    for (int k = tid; k < n; k += 256) mloc = fmaxf(mloc, sc[k]);
    mloc = wmax_all(mloc);
    if ((tid & 63) == 0) red[tid >> 6] = mloc;
    __syncthreads();
    if (tid == 0) sh_m = fmaxf(fmaxf(red[0], red[1]), fmaxf(red[2], red[3]));
    __syncthreads();
    float m = sh_m;
    float sloc = 0.f;
    for (int k = tid; k < n; k += 256) sloc += expf(sc[k] - m);
    sloc = wred_all(sloc);
    __syncthreads();
    if ((tid & 63) == 0) red[tid >> 6] = sloc;
    __syncthreads();
    if (tid == 0) sh_s = red[0] + red[1] + red[2] + red[3];
    __syncthreads();
    float inv = 1.f / sh_s;
    int cc = i & 3;
    int r0 = (i >> 2) * 32;
    int col = cc * 256 + tid;
    float acc = 0.f;
    #pragma unroll 8
    for (int r = r0; r < r0 + 32; ++r) acc += expf(sc[r] - m) * src[(size_t)r * HH + col];
    atomicAdd(&dst[col], acc * inv);
}

// K4: x = tanh(W_ma_comb @ comb + b)   (512 rows x 3584)
__global__ void k_x(const float* __restrict__ W, const float* __restrict__ bias,
                    float* __restrict__ ws) {
    int tid = threadIdx.x, wave = tid >> 6, lane = tid & 63;
    int row = blockIdx.x * 4 + wave;                   // < 512
    const float4* Wr = (const float4*)(W + (size_t)row * 3584);
    const float4* c4 = (const float4*)(ws + OFF_COMB);
    float s = 0.f;
    #pragma unroll
    for (int k = 0; k < 14; ++k) s += dot4(Wr[lane + 64 * k], c4[lane + 64 * k]);
    s = wred(s);
    if (lane == 0) ws[OFF_X + row] = tanhf(s + bias[row]);
}

// K5: gates = W_ih @ x + W_hh @ h0 + b_ih + b_hh   (4096 rows)
__global__ void k_gates(const float* __restrict__ Wih, const float* __restrict__ Whh,
                        const float* __restrict__ bih, const float* __restrict__ bhh,
                        const float* __restrict__ h0, float* __restrict__ ws) {
    int tid = threadIdx.x, wave = tid >> 6, lane = tid & 63;
    int row0 = (blockIdx.x * 4 + wave) * 4;            // < 4096
    const float4* x4 = (const float4*)(ws + OFF_X);
    float4 xv[2] = { x4[lane], x4[lane + 64] };
    const float4* h4 = (const float4*)h0;
    float4 hv[4] = { h4[lane], h4[lane + 64], h4[lane + 128], h4[lane + 192] };
    float s1[4], s2[4];
    rowsN_dot<4, 2>(Wih, EE, row0, 4095, xv, lane, s1);
    rowsN_dot<4, 4>(Whh, HH, row0, 4095, hv, lane, s2);
    #pragma unroll
    for (int r = 0; r < 4; ++r) {
        float v = wred(s1[r] + s2[r]);
        int row = row0 + r;
        if (lane == 0) ws[OFF_GATES + row] = v + bih[row] + bhh[row];
    }
}

// K6: LSTM cell -> h1,c1 (to ws and d_out); then gen_p
__global__ void k_lstm(const float* __restrict__ c0, const float* __restrict__ nameh,
                       const float* __restrict__ typeh, const float* __restrict__ Wg,
                       const float* __restrict__ bg, float* __restrict__ ws,
                       float* __restrict__ out) {
    int t = threadIdx.x;                               // 1024 threads
    float ig = ws[OFF_GATES + t], fg = ws[OFF_GATES + 1024 + t];
    float gg = ws[OFF_GATES + 2048 + t], og = ws[OFF_GATES + 3072 + t];
    ig = 1.f / (1.f + expf(-ig));
    fg = 1.f / (1.f + expf(-fg));
    og = 1.f / (1.f + expf(-og));
    float c1 = fg * c0[t] + ig * tanhf(gg);
    float h1 = og * tanhf(c1);
    ws[OFF_C1 + t] = c1; ws[OFF_H1 + t] = h1;
    out[VV + MOOV + t] = h1;
    out[VV + MOOV + 1024 + t] = c1;
    __syncthreads();
    float p = Wg[t] * h1 + Wg[1024 + t] * nameh[t] + Wg[2048 + t] * typeh[t];
    if (t < 512) p += Wg[3072 + t] * ws[OFF_X + t];
    __shared__ float red[16];
    float su = p;
    #pragma unroll
    for (int o = 32; o; o >>= 1) su += __shfl_xor(su, o, 64);
    if ((t & 63) == 0) red[t >> 6] = su;
    __syncthreads();
    if (t == 0) {
        float ss = 0.f;
        for (int i = 0; i < 16; ++i) ss += red[i];
        ws[OFF_GENP] = 1.f / (1.f + expf(-(ss + bg[0])));
    }
}

// K7: qc = W_copy @ h1 + b_copy  (1024 rows)
__global__ void k_qc(const float* __restrict__ W, const float* __restrict__ bias,
                     float* __restrict__ ws) {
    int tid = threadIdx.x, wave = tid >> 6, lane = tid & 63;
    int row0 = (blockIdx.x * 4 + wave) * 4;            // < 1024
    const float4* h4 = (const float4*)(ws + OFF_H1);
    float4 hv[4] = { h4[lane], h4[lane + 64], h4[lane + 128], h4[lane + 192] };
    float s[4];
    rowsN_dot<4, 4>(W, HH, row0, 1023, hv, lane, s);
    #pragma unroll
    for (int r = 0; r < 4; ++r) {
        float v = wred(s[r]);
        if (lane == 0) ws[OFF_QC + row0 + r] = v + bias[row0 + r];
    }
}

// K8: per-s: scores = type_hiddens[s,:,:] @ qc, softmax, scale by (1-gp)*sim[s],
// scatter-add into ws pcopy. 8 blocks (one per s) x 256 threads.
__global__ void k_attn_scatter(const float* __restrict__ type, const int* __restrict__ idx,
                               float* __restrict__ ws) {
    __shared__ float sc[TSS];
    __shared__ float sh_m, sh_s;
    int s = blockIdx.x, tid = threadIdx.x;
    int wave = tid >> 6, lane = tid & 63;
    const float4* q4 = (const float4*)(ws + OFF_QC);
    float4 qv[4] = { q4[lane], q4[lane + 64], q4[lane + 128], q4[lane + 192] };
    // each wave: 32 rows
    #pragma unroll
    for (int g = 0; g < 8; ++g) {
        int rloc = wave * 32 + g * 4;
        int r0 = s * TSS + rloc;
        float sv[4];
        rowsN_dot<4, 4>(type, HH, r0, 1 << 30, qv, lane, sv);
        #pragma unroll
        for (int r = 0; r < 4; ++r) {
            float v = wred(sv[r]);
            if (lane == 0) sc[rloc + r] = v;
        }
    }
    __syncthreads();
    if (wave == 0) {
        float v0 = sc[lane], v1 = sc[lane + 64];
        float m = wmax_all(fmaxf(v0, v1));
        float su = wred_all(expf(v0 - m) + expf(v1 - m));
        if (lane == 0) { sh_m = m; sh_s = su; }
    }
    __syncthreads();
    if (tid < TSS) {
        float scale = (1.f - ws[OFF_GENP]) * ws[OFF_SIM + s] / sh_s;
        float w = scale * expf(sc[tid] - sh_m);
        atomicAdd(&ws[OFF_PCOPY + idx[s * TSS + tid]], w);
    }
}

// K9: big matvec exp(W_out @ h1 + b_out); 8 rows/wave, 32 loads in flight
__global__ void k_big(const float* __restrict__ W, const float* __restrict__ bias,
                      float* __restrict__ ws) {
    __shared__ float4 sh[256];
    __shared__ float part[4];
    int tid = threadIdx.x, wave = tid >> 6, lane = tid & 63;
    sh[tid] = ((const float4*)(ws + OFF_H1))[tid];
    __syncthreads();
    float4 hv[4] = { sh[lane], sh[lane + 64], sh[lane + 128], sh[lane + 192] };
    int row0 = (blockIdx.x * 4 + wave) * 8;
    float s[8];
    rowsN_dot<8, 4>(W, HH, row0, VV - 1, hv, lane, s);
    float partial = 0.f;
    #pragma unroll
    for (int r = 0; r < 8; ++r) {
        float v = wred(s[r]);
        int row = row0 + r;
        if (lane == 0 && row < VV) {
            float e = expf(v + bias[row]);
            ws[OFF_LOGIT + row] = e;
            partial += e;
        }
    }
    if (lane == 0) part[wave] = partial;
    __syncthreads();
    if (tid == 0) atomicAdd(&ws[OFF_SUMEXP], part[0] + part[1] + part[2] + part[3]);
}

// K10: out[v] = log(clip(gen_p * p_vocab[v] + p_copy[v]))
__global__ void k_final(const float* __restrict__ ws, float* __restrict__ out) {
    int g = blockIdx.x * 256 + threadIdx.x;
    if (g >= VV + MOOV) return;
    float gp = ws[OFF_GENP];
    float pv = (g < VV) ? ws[OFF_LOGIT + g] / ws[OFF_SUMEXP] : 0.f;
    float prob = gp * pv + ws[OFF_PCOPY + g];
    out[g] = logf(fmaxf(prob, 1e-10f));
}

extern "C" void kernel_launch(void* const* d_in, const int* in_sizes, int n_in,
                              void* d_out, int out_size, void* d_ws, size_t ws_size,
                              hipStream_t stream) {
    (void)in_sizes; (void)n_in; (void)out_size; (void)ws_size;
    const float* emb   = (const float*)d_in[0];
    const float* h0    = (const float*)d_in[1];
    const float* c0    = (const float*)d_in[2];
    const float* enc   = (const float*)d_in[3];
    const float* name  = (const float*)d_in[4];
    const float* type  = (const float*)d_in[5];
    const float* nameh = (const float*)d_in[6];
    const float* typeh = (const float*)d_in[7];
    const float* Wma   = (const float*)d_in[8];
    const float* bma   = (const float*)d_in[9];
    const float* Wmc   = (const float*)d_in[10];
    const float* bmc   = (const float*)d_in[11];
    const float* Wih   = (const float*)d_in[12];
    const float* Whh   = (const float*)d_in[13];
    const float* bih   = (const float*)d_in[14];
    const float* bhh   = (const float*)d_in[15];
    const float* Wcp   = (const float*)d_in[16];
    const float* bcp   = (const float*)d_in[17];
    const float* Wg    = (const float*)d_in[18];
    const float* bg    = (const float*)d_in[19];
    const float* Wout  = (const float*)d_in[20];
    const float* bout  = (const float*)d_in[21];
    const int*   tidx  = (const int*)d_in[22];
    float* out = (float*)d_out;
    float* ws  = (float*)d_ws;

    k_init_q      <<<197,  256, 0, stream>>>(emb, Wma, bma, ws);
    k_scores      <<<161,  256, 0, stream>>>(enc, name, type, ws);
    k_ctx         <<<320,  256, 0, stream>>>(enc, name, type, ws);
    k_x           <<<128,  256, 0, stream>>>(Wmc, bmc, ws);
    k_gates       <<<256,  256, 0, stream>>>(Wih, Whh, bih, bhh, h0, ws);
    k_lstm        <<<1,   1024, 0, stream>>>(c0, nameh, typeh, Wg, bg, ws, out);
    k_qc          <<<64,   256, 0, stream>>>(Wcp, bcp, ws);
    k_attn_scatter<<<8,    256, 0, stream>>>(type, tidx, ws);
    k_big         <<<1571, 256, 0, stream>>>(Wout, bout, ws);
    k_final       <<<197,  256, 0, stream>>>(ws, out);
}

// Round 4
// 84.131 us; speedup vs baseline: 1.3527x; 1.3527x over previous
//
#include <hip/hip_runtime.h>

#define VV   50257
#define EE   512
#define HH   1024
#define TT   512
#define SS   8
#define TSS  128
#define MOOV 20

// ws layout (floats)
#define OFF_Q      0        // 1024
#define OFF_COMB   1024     // 3584 : [emb(512) | acc_enc(1024) | acc_name(1024) | acc_type(1024)]
#define OFF_DENOM  4608     // 3 : unnormalized softmax denominators (enc, name, type)
#define OFF_SUMPART 4640    // 32 slots spaced 32 floats (128 B) for k_big partial sumexp
#define OFF_X      7168     // 512
#define OFF_H1     11776    // 1024
#define OFF_C1     12800    // 1024
#define OFF_GENP   13824    // 1
#define OFF_SIM    13832    // 8
#define OFF_QC     13840    // 1024
#define OFF_LOGIT  15888    // 50257 (stores exp(logit))
#define OFF_PCOPY  66148    // 50277 (scaled copy probs, zeroed each call)

__device__ __forceinline__ float dot4(float4 a, float4 b) {
    return a.x*b.x + a.y*b.y + a.z*b.z + a.w*b.w;
}
__device__ __forceinline__ float wred(float v) {
    #pragma unroll
    for (int o = 32; o; o >>= 1) v += __shfl_down(v, o, 64);
    return v;
}
__device__ __forceinline__ float wred_all(float v) {
    #pragma unroll
    for (int o = 32; o; o >>= 1) v += __shfl_xor(v, o, 64);
    return v;
}
__device__ __forceinline__ float wmax_all(float v) {
    #pragma unroll
    for (int o = 32; o; o >>= 1) v = fmaxf(v, __shfl_xor(v, o, 64));
    return v;
}

// R rows per wave, CH float4-chunks per lane per row; vector held in registers.
template<int R, int CH>
__device__ __forceinline__ void rowsN_dot(const float* __restrict__ W, int ld,
                                          int row0, int rowmax,
                                          const float4 vec[CH], int lane, float s[R]) {
    float4 w[R][CH];
    #pragma unroll
    for (int r = 0; r < R; ++r) {
        int row = row0 + r; if (row > rowmax) row = rowmax;
        const float4* Wr = (const float4*)(W + (size_t)row * ld);
        #pragma unroll
        for (int k = 0; k < CH; ++k) w[r][k] = Wr[lane + 64 * k];
    }
    #pragma unroll
    for (int r = 0; r < R; ++r) {
        float acc = 0.f;
        #pragma unroll
        for (int k = 0; k < CH; ++k) acc += dot4(w[r][k], vec[k]);
        s[r] = acc;
    }
}

// K1: zero scratch (comb acc, denoms, sumparts, pcopy), copy emb, q = W_ma_attn @ emb + b
__global__ void k_init_q(const float* __restrict__ emb, const float* __restrict__ W,
                         const float* __restrict__ bias, float* __restrict__ ws) {
    int tid = threadIdx.x, bid = blockIdx.x;
    int gid = bid * 256 + tid;
    if (gid < 3072) ws[OFF_COMB + 512 + gid] = 0.f;
    if (gid < 3)    ws[OFF_DENOM + gid] = 0.f;
    if (gid < 1024) ws[OFF_SUMPART + gid] = 0.f;
    if (gid < 512)  ws[OFF_COMB + gid] = emb[gid];
    if (gid < VV + MOOV) ws[OFF_PCOPY + gid] = 0.f;
    if (bid >= 64) return;
    int wave = tid >> 6, lane = tid & 63;
    const float4* e4 = (const float4*)emb;
    float4 ev[2] = { e4[lane], e4[lane + 64] };
    int row0 = (bid * 4 + wave) * 4;                   // < 1024
    float s[4];
    rowsN_dot<4, 2>(W, EE, row0, 1023, ev, lane, s);
    #pragma unroll
    for (int r = 0; r < 4; ++r) {
        float v = wred(s[r]);
        if (lane == 0) ws[OFF_Q + row0 + r] = v + bias[row0 + r];
    }
}

// K2: fused scores + unnormalized-softmax context accumulation (+ sim in block 160)
// Blocks 0..159: 16 rows of one segment each. Compute e^(row.q), then
// acc_seg[col] += sum_r e_r * row_r[col] and denom_seg += sum_r e_r (atomics).
__global__ void k_scores_ctx(const float* __restrict__ enc, const float* __restrict__ name,
                             const float* __restrict__ type, float* __restrict__ ws) {
    int b = blockIdx.x, tid = threadIdx.x;
    int wave = tid >> 6, lane = tid & 63;
    if (b < 160) {
        const float* src; int seg, lb;
        if (b < 32)      { src = enc;  seg = 0; lb = b; }
        else if (b < 96) { src = name; seg = 1; lb = b - 32; }
        else             { src = type; seg = 2; lb = b - 96; }
        __shared__ float sc[16];
        const float4* q4 = (const float4*)(ws + OFF_Q);
        float4 qv[4] = { q4[lane], q4[lane + 64], q4[lane + 128], q4[lane + 192] };
        int r0 = lb * 16 + wave * 4;
        float s[4];
        rowsN_dot<4, 4>(src, HH, r0, 1 << 30, qv, lane, s);
        #pragma unroll
        for (int r = 0; r < 4; ++r) {
            float v = wred(s[r]);
            if (lane == 0) sc[wave * 4 + r] = __expf(v);
        }
        __syncthreads();
        // weighted accumulation: thread owns cols tid + 256*c
        float acc[4] = {0.f, 0.f, 0.f, 0.f};
        const float* base = src + (size_t)(lb * 16) * HH;
        #pragma unroll 4
        for (int r = 0; r < 16; ++r) {
            float er = sc[r];
            const float* row = base + (size_t)r * HH;
            #pragma unroll
            for (int c = 0; c < 4; ++c) acc[c] += er * row[tid + 256 * c];
        }
        float* dst = ws + OFF_COMB + 512 + seg * 1024;
        #pragma unroll
        for (int c = 0; c < 4; ++c) atomicAdd(&dst[tid + 256 * c], acc[c]);
        if (tid == 0) {
            float es = 0.f;
            for (int r = 0; r < 16; ++r) es += sc[r];
            atomicAdd(&ws[OFF_DENOM + seg], es);
        }
    } else {
        // sim = softmax(enc_last @ name_hiddens[:, -1, :].T)
        __shared__ float sd[8];
        const float4* el = (const float4*)(enc + (size_t)(TT - 1) * HH);
        for (int s8 = wave; s8 < 8; s8 += 4) {
            const float4* R = (const float4*)(name + ((size_t)s8 * TSS + (TSS - 1)) * HH);
            float s = 0.f;
            #pragma unroll
            for (int k = 0; k < 4; ++k) s += dot4(R[lane + 64 * k], el[lane + 64 * k]);
            s = wred(s);
            if (lane == 0) sd[s8] = s;
        }
        __syncthreads();
        if (tid == 0) {
            float m = -1e30f;
            for (int i = 0; i < 8; ++i) m = fmaxf(m, sd[i]);
            float e[8], su = 0.f;
            for (int i = 0; i < 8; ++i) { e[i] = expf(sd[i] - m); su += e[i]; }
            for (int i = 0; i < 8; ++i) ws[OFF_SIM + i] = e[i] / su;
        }
    }
}

// K3: x = tanh(W_ma_comb @ (comb with per-segment 1/denom scaling) + b)
__global__ void k_x(const float* __restrict__ W, const float* __restrict__ bias,
                    float* __restrict__ ws) {
    int tid = threadIdx.x, wave = tid >> 6, lane = tid & 63;
    int row = blockIdx.x * 4 + wave;                   // < 512
    float inv1 = 1.f / ws[OFF_DENOM + 0];
    float inv2 = 1.f / ws[OFF_DENOM + 1];
    float inv3 = 1.f / ws[OFF_DENOM + 2];
    const float4* Wr = (const float4*)(W + (size_t)row * 3584);
    const float4* c4 = (const float4*)(ws + OFF_COMB);
    float s = 0.f;
    #pragma unroll
    for (int k = 0; k < 14; ++k) {
        int j = lane + 64 * k;
        float sc = (j < 128) ? 1.f : (j < 384) ? inv1 : (j < 640) ? inv2 : inv3;
        s += dot4(Wr[j], c4[j]) * sc;
    }
    s = wred(s);
    if (lane == 0) ws[OFF_X + row] = tanhf(s + bias[row]);
}

// K4: fused gates + LSTM cell. Block b owns t in [b*16, b*16+16).
// Wave w computes gate w's 16 rows; then first 16 threads finish c1/h1.
__global__ void k_gates_lstm(const float* __restrict__ Wih, const float* __restrict__ Whh,
                             const float* __restrict__ bih, const float* __restrict__ bhh,
                             const float* __restrict__ h0, const float* __restrict__ c0,
                             float* __restrict__ ws, float* __restrict__ out) {
    __shared__ float g4[4][16];
    int tid = threadIdx.x, wave = tid >> 6, lane = tid & 63, b = blockIdx.x;
    const float4* x4 = (const float4*)(ws + OFF_X);
    float4 xv[2] = { x4[lane], x4[lane + 64] };
    const float4* h4 = (const float4*)h0;
    float4 hv[4] = { h4[lane], h4[lane + 64], h4[lane + 128], h4[lane + 192] };
    #pragma unroll
    for (int grp = 0; grp < 4; ++grp) {
        int row0 = wave * 1024 + b * 16 + grp * 4;
        float s1[4], s2[4];
        rowsN_dot<4, 2>(Wih, EE, row0, 4095, xv, lane, s1);
        rowsN_dot<4, 4>(Whh, HH, row0, 4095, hv, lane, s2);
        #pragma unroll
        for (int r = 0; r < 4; ++r) {
            float v = wred(s1[r] + s2[r]);
            int row = row0 + r;
            if (lane == 0) g4[wave][grp * 4 + r] = v + bih[row] + bhh[row];
        }
    }
    __syncthreads();
    if (tid < 16) {
        int t = b * 16 + tid;
        float ig = 1.f / (1.f + expf(-g4[0][tid]));
        float fg = 1.f / (1.f + expf(-g4[1][tid]));
        float gg = tanhf(g4[2][tid]);
        float og = 1.f / (1.f + expf(-g4[3][tid]));
        float c1 = fg * c0[t] + ig * gg;
        float h1 = og * tanhf(c1);
        ws[OFF_H1 + t] = h1; ws[OFF_C1 + t] = c1;
        out[VV + MOOV + t] = h1;
        out[VV + MOOV + 1024 + t] = c1;
    }
}

// K5: big matvec exp(W_out @ h1 + b_out); 4 rows/wave; spread partial sumexp
__global__ void k_big(const float* __restrict__ W, const float* __restrict__ bias,
                      float* __restrict__ ws) {
    __shared__ float4 sh[256];
    __shared__ float part[4];
    int tid = threadIdx.x, wave = tid >> 6, lane = tid & 63;
    sh[tid] = ((const float4*)(ws + OFF_H1))[tid];
    __syncthreads();
    float4 hv[4] = { sh[lane], sh[lane + 64], sh[lane + 128], sh[lane + 192] };
    int row0 = (blockIdx.x * 4 + wave) * 4;
    float s[4];
    rowsN_dot<4, 4>(W, HH, row0, VV - 1, hv, lane, s);
    float partial = 0.f;
    #pragma unroll
    for (int r = 0; r < 4; ++r) {
        float v = wred(s[r]);
        int row = row0 + r;
        if (lane == 0 && row < VV) {
            float e = expf(v + bias[row]);
            ws[OFF_LOGIT + row] = e;
            partial += e;
        }
    }
    if (lane == 0) part[wave] = partial;
    __syncthreads();
    if (tid == 0)
        atomicAdd(&ws[OFF_SUMPART + (blockIdx.x & 31) * 32],
                  part[0] + part[1] + part[2] + part[3]);
}

// K6: qc = W_copy @ h1 + b_copy (blocks 0..63); gen_p (block 64)
__global__ void k_qc_genp(const float* __restrict__ W, const float* __restrict__ bias,
                          const float* __restrict__ nameh, const float* __restrict__ typeh,
                          const float* __restrict__ Wg, const float* __restrict__ bg,
                          float* __restrict__ ws) {
    int tid = threadIdx.x, wave = tid >> 6, lane = tid & 63, b = blockIdx.x;
    if (b < 64) {
        int row0 = (b * 4 + wave) * 4;                 // < 1024
        const float4* h4 = (const float4*)(ws + OFF_H1);
        float4 hv[4] = { h4[lane], h4[lane + 64], h4[lane + 128], h4[lane + 192] };
        float s[4];
        rowsN_dot<4, 4>(W, HH, row0, 1023, hv, lane, s);
        #pragma unroll
        for (int r = 0; r < 4; ++r) {
            float v = wred(s[r]);
            if (lane == 0) ws[OFF_QC + row0 + r] = v + bias[row0 + r];
        }
    } else {
        // gen_p = sigmoid(W_gen . [h1, name_h, type_h, x] + b_gen)
        float p = 0.f;
        #pragma unroll
        for (int j = 0; j < 14; ++j) {
            int k = tid + 256 * j;
            float cat = (k < 1024) ? ws[OFF_H1 + k]
                      : (k < 2048) ? nameh[k - 1024]
                      : (k < 3072) ? typeh[k - 2048]
                                   : ws[OFF_X + k - 3072];
            p += Wg[k] * cat;
        }
        __shared__ float red[4];
        float su = wred_all(p);
        if ((tid & 63) == 0) red[tid >> 6] = su;
        __syncthreads();
        if (tid == 0) {
            float ss = red[0] + red[1] + red[2] + red[3];
            ws[OFF_GENP] = 1.f / (1.f + expf(-(ss + bg[0])));
        }
    }
}

// K7: per-s: scores = type_hiddens[s] @ qc, softmax, scale, scatter into pcopy
__global__ void k_attn_scatter(const float* __restrict__ type, const int* __restrict__ idx,
                               float* __restrict__ ws) {
    __shared__ float sc[TSS];
    __shared__ float sh_m, sh_s;
    int s = blockIdx.x, tid = threadIdx.x;
    int wave = tid >> 6, lane = tid & 63;
    const float4* q4 = (const float4*)(ws + OFF_QC);
    float4 qv[4] = { q4[lane], q4[lane + 64], q4[lane + 128], q4[lane + 192] };
    #pragma unroll
    for (int g = 0; g < 8; ++g) {
        int rloc = wave * 32 + g * 4;
        int r0 = s * TSS + rloc;
        float sv[4];
        rowsN_dot<4, 4>(type, HH, r0, 1 << 30, qv, lane, sv);
        #pragma unroll
        for (int r = 0; r < 4; ++r) {
            float v = wred(sv[r]);
            if (lane == 0) sc[rloc + r] = v;
        }
    }
    __syncthreads();
    if (wave == 0) {
        float v0 = sc[lane], v1 = sc[lane + 64];
        float m = wmax_all(fmaxf(v0, v1));
        float su = wred_all(expf(v0 - m) + expf(v1 - m));
        if (lane == 0) { sh_m = m; sh_s = su; }
    }
    __syncthreads();
    if (tid < TSS) {
        float scale = (1.f - ws[OFF_GENP]) * ws[OFF_SIM + s] / sh_s;
        float w = scale * expf(sc[tid] - sh_m);
        atomicAdd(&ws[OFF_PCOPY + idx[s * TSS + tid]], w);
    }
}

// K8: out[v] = log(clip(gen_p * p_vocab[v] + p_copy[v]))
__global__ void k_final(const float* __restrict__ ws, float* __restrict__ out) {
    __shared__ float ssum;
    int tid = threadIdx.x;
    if (tid < 64) {
        float v = (tid < 32) ? ws[OFF_SUMPART + tid * 32] : 0.f;
        v = wred_all(v);
        if (tid == 0) ssum = v;
    }
    __syncthreads();
    int g = blockIdx.x * 256 + tid;
    if (g >= VV + MOOV) return;
    float gp = ws[OFF_GENP];
    float pv = (g < VV) ? ws[OFF_LOGIT + g] / ssum : 0.f;
    float prob = gp * pv + ws[OFF_PCOPY + g];
    out[g] = logf(fmaxf(prob, 1e-10f));
}

extern "C" void kernel_launch(void* const* d_in, const int* in_sizes, int n_in,
                              void* d_out, int out_size, void* d_ws, size_t ws_size,
                              hipStream_t stream) {
    (void)in_sizes; (void)n_in; (void)out_size; (void)ws_size;
    const float* emb   = (const float*)d_in[0];
    const float* h0    = (const float*)d_in[1];
    const float* c0    = (const float*)d_in[2];
    const float* enc   = (const float*)d_in[3];
    const float* name  = (const float*)d_in[4];
    const float* type  = (const float*)d_in[5];
    const float* nameh = (const float*)d_in[6];
    const float* typeh = (const float*)d_in[7];
    const float* Wma   = (const float*)d_in[8];
    const float* bma   = (const float*)d_in[9];
    const float* Wmc   = (const float*)d_in[10];
    const float* bmc   = (const float*)d_in[11];
    const float* Wih   = (const float*)d_in[12];
    const float* Whh   = (const float*)d_in[13];
    const float* bih   = (const float*)d_in[14];
    const float* bhh   = (const float*)d_in[15];
    const float* Wcp   = (const float*)d_in[16];
    const float* bcp   = (const float*)d_in[17];
    const float* Wg    = (const float*)d_in[18];
    const float* bg    = (const float*)d_in[19];
    const float* Wout  = (const float*)d_in[20];
    const float* bout  = (const float*)d_in[21];
    const int*   tidx  = (const int*)d_in[22];
    float* out = (float*)d_out;
    float* ws  = (float*)d_ws;

    k_init_q      <<<197,  256, 0, stream>>>(emb, Wma, bma, ws);
    k_scores_ctx  <<<161,  256, 0, stream>>>(enc, name, type, ws);
    k_x           <<<128,  256, 0, stream>>>(Wmc, bmc, ws);
    k_gates_lstm  <<<64,   256, 0, stream>>>(Wih, Whh, bih, bhh, h0, c0, ws, out);
    k_big         <<<3142, 256, 0, stream>>>(Wout, bout, ws);
    k_qc_genp     <<<65,   256, 0, stream>>>(Wcp, bcp, nameh, typeh, Wg, bg, ws);
    k_attn_scatter<<<8,    256, 0, stream>>>(type, tidx, ws);
    k_final       <<<197,  256, 0, stream>>>(ws, out);
}

// Round 5
// 80.965 us; speedup vs baseline: 1.4056x; 1.0391x over previous
//
#include <hip/hip_runtime.h>

#define VV   50257
#define EE   512
#define HH   1024
#define TT   512
#define SS   8
#define TSS  128
#define MOOV 20

// ws layout (floats)
#define OFF_Q      0        // 1024
#define OFF_COMB   1024     // 3584 : [emb(512) | acc_enc(1024) | acc_name(1024) | acc_type(1024)]
#define OFF_DENOM  4608     // 3 : unnormalized softmax denominators (enc, name, type)
#define OFF_SUMPART 4640    // 32 slots spaced 32 floats (128 B) for k_big partial sumexp
#define OFF_X      7168     // 512
#define OFF_H1     11776    // 1024
#define OFF_C1     12800    // 1024
#define OFF_GENP   13824    // 1
#define OFF_SIM    13832    // 8
#define OFF_QC     13840    // 1024
#define OFF_LOGIT  15888    // 50257 (stores exp(logit))
#define OFF_PCOPY  66148    // 50277 (scaled copy probs, zeroed each call)

#define NBIG 3142           // blocks covering VV rows at 16 rows/block

__device__ __forceinline__ float dot4(float4 a, float4 b) {
    return a.x*b.x + a.y*b.y + a.z*b.z + a.w*b.w;
}
__device__ __forceinline__ float wred(float v) {
    #pragma unroll
    for (int o = 32; o; o >>= 1) v += __shfl_down(v, o, 64);
    return v;
}
__device__ __forceinline__ float wred_all(float v) {
    #pragma unroll
    for (int o = 32; o; o >>= 1) v += __shfl_xor(v, o, 64);
    return v;
}
__device__ __forceinline__ float wmax_all(float v) {
    #pragma unroll
    for (int o = 32; o; o >>= 1) v = fmaxf(v, __shfl_xor(v, o, 64));
    return v;
}

// R rows per wave, CH float4-chunks per lane per row; vector held in registers.
template<int R, int CH>
__device__ __forceinline__ void rowsN_dot(const float* __restrict__ W, int ld,
                                          int row0, int rowmax,
                                          const float4 vec[CH], int lane, float s[R]) {
    float4 w[R][CH];
    #pragma unroll
    for (int r = 0; r < R; ++r) {
        int row = row0 + r; if (row > rowmax) row = rowmax;
        const float4* Wr = (const float4*)(W + (size_t)row * ld);
        #pragma unroll
        for (int k = 0; k < CH; ++k) w[r][k] = Wr[lane + 64 * k];
    }
    #pragma unroll
    for (int r = 0; r < R; ++r) {
        float acc = 0.f;
        #pragma unroll
        for (int k = 0; k < CH; ++k) acc += dot4(w[r][k], vec[k]);
        s[r] = acc;
    }
}

// K1: zero scratch (comb acc, denoms, sumparts, pcopy), copy emb, q = W_ma_attn @ emb + b
__global__ void k_init_q(const float* __restrict__ emb, const float* __restrict__ W,
                         const float* __restrict__ bias, float* __restrict__ ws) {
    int tid = threadIdx.x, bid = blockIdx.x;
    int gid = bid * 256 + tid;
    if (gid < 3072) ws[OFF_COMB + 512 + gid] = 0.f;
    if (gid < 3)    ws[OFF_DENOM + gid] = 0.f;
    if (gid < 1024) ws[OFF_SUMPART + gid] = 0.f;
    if (gid < 512)  ws[OFF_COMB + gid] = emb[gid];
    if (gid < VV + MOOV) ws[OFF_PCOPY + gid] = 0.f;
    if (bid >= 64) return;
    int wave = tid >> 6, lane = tid & 63;
    const float4* e4 = (const float4*)emb;
    float4 ev[2] = { e4[lane], e4[lane + 64] };
    int row0 = (bid * 4 + wave) * 4;                   // < 1024
    float s[4];
    rowsN_dot<4, 2>(W, EE, row0, 1023, ev, lane, s);
    #pragma unroll
    for (int r = 0; r < 4; ++r) {
        float v = wred(s[r]);
        if (lane == 0) ws[OFF_Q + row0 + r] = v + bias[row0 + r];
    }
}

// K2: fused scores + unnormalized-softmax context accumulation (+ sim in block 160)
__global__ void k_scores_ctx(const float* __restrict__ enc, const float* __restrict__ name,
                             const float* __restrict__ type, float* __restrict__ ws) {
    int b = blockIdx.x, tid = threadIdx.x;
    int wave = tid >> 6, lane = tid & 63;
    if (b < 160) {
        const float* src; int seg, lb;
        if (b < 32)      { src = enc;  seg = 0; lb = b; }
        else if (b < 96) { src = name; seg = 1; lb = b - 32; }
        else             { src = type; seg = 2; lb = b - 96; }
        __shared__ float sc[16];
        const float4* q4 = (const float4*)(ws + OFF_Q);
        float4 qv[4] = { q4[lane], q4[lane + 64], q4[lane + 128], q4[lane + 192] };
        int r0 = lb * 16 + wave * 4;
        float s[4];
        rowsN_dot<4, 4>(src, HH, r0, 1 << 30, qv, lane, s);
        #pragma unroll
        for (int r = 0; r < 4; ++r) {
            float v = wred(s[r]);
            if (lane == 0) sc[wave * 4 + r] = __expf(v);
        }
        __syncthreads();
        float acc[4] = {0.f, 0.f, 0.f, 0.f};
        const float* base = src + (size_t)(lb * 16) * HH;
        #pragma unroll 4
        for (int r = 0; r < 16; ++r) {
            float er = sc[r];
            const float* row = base + (size_t)r * HH;
            #pragma unroll
            for (int c = 0; c < 4; ++c) acc[c] += er * row[tid + 256 * c];
        }
        float* dst = ws + OFF_COMB + 512 + seg * 1024;
        #pragma unroll
        for (int c = 0; c < 4; ++c) atomicAdd(&dst[tid + 256 * c], acc[c]);
        if (tid == 0) {
            float es = 0.f;
            for (int r = 0; r < 16; ++r) es += sc[r];
            atomicAdd(&ws[OFF_DENOM + seg], es);
        }
    } else {
        __shared__ float sd[8];
        const float4* el = (const float4*)(enc + (size_t)(TT - 1) * HH);
        for (int s8 = wave; s8 < 8; s8 += 4) {
            const float4* R = (const float4*)(name + ((size_t)s8 * TSS + (TSS - 1)) * HH);
            float s = 0.f;
            #pragma unroll
            for (int k = 0; k < 4; ++k) s += dot4(R[lane + 64 * k], el[lane + 64 * k]);
            s = wred(s);
            if (lane == 0) sd[s8] = s;
        }
        __syncthreads();
        if (tid == 0) {
            float m = -1e30f;
            for (int i = 0; i < 8; ++i) m = fmaxf(m, sd[i]);
            float e[8], su = 0.f;
            for (int i = 0; i < 8; ++i) { e[i] = expf(sd[i] - m); su += e[i]; }
            for (int i = 0; i < 8; ++i) ws[OFF_SIM + i] = e[i] / su;
        }
    }
}

// K3: x = tanh(W_ma_comb @ (comb with per-segment 1/denom scaling) + b)
__global__ void k_x(const float* __restrict__ W, const float* __restrict__ bias,
                    float* __restrict__ ws) {
    int tid = threadIdx.x, wave = tid >> 6, lane = tid & 63;
    int row = blockIdx.x * 4 + wave;                   // < 512
    float inv1 = 1.f / ws[OFF_DENOM + 0];
    float inv2 = 1.f / ws[OFF_DENOM + 1];
    float inv3 = 1.f / ws[OFF_DENOM + 2];
    const float4* Wr = (const float4*)(W + (size_t)row * 3584);
    const float4* c4 = (const float4*)(ws + OFF_COMB);
    float s = 0.f;
    #pragma unroll
    for (int k = 0; k < 14; ++k) {
        int j = lane + 64 * k;
        float sc = (j < 128) ? 1.f : (j < 384) ? inv1 : (j < 640) ? inv2 : inv3;
        s += dot4(Wr[j], c4[j]) * sc;
    }
    s = wred(s);
    if (lane == 0) ws[OFF_X + row] = tanhf(s + bias[row]);
}

// K4: fused gates + LSTM cell. Block b owns t in [b*16, b*16+16).
__global__ void k_gates_lstm(const float* __restrict__ Wih, const float* __restrict__ Whh,
                             const float* __restrict__ bih, const float* __restrict__ bhh,
                             const float* __restrict__ h0, const float* __restrict__ c0,
                             float* __restrict__ ws, float* __restrict__ out) {
    __shared__ float g4[4][16];
    int tid = threadIdx.x, wave = tid >> 6, lane = tid & 63, b = blockIdx.x;
    const float4* x4 = (const float4*)(ws + OFF_X);
    float4 xv[2] = { x4[lane], x4[lane + 64] };
    const float4* h4 = (const float4*)h0;
    float4 hv[4] = { h4[lane], h4[lane + 64], h4[lane + 128], h4[lane + 192] };
    #pragma unroll
    for (int grp = 0; grp < 4; ++grp) {
        int row0 = wave * 1024 + b * 16 + grp * 4;
        float s1[4], s2[4];
        rowsN_dot<4, 2>(Wih, EE, row0, 4095, xv, lane, s1);
        rowsN_dot<4, 4>(Whh, HH, row0, 4095, hv, lane, s2);
        #pragma unroll
        for (int r = 0; r < 4; ++r) {
            float v = wred(s1[r] + s2[r]);
            int row = row0 + r;
            if (lane == 0) g4[wave][grp * 4 + r] = v + bih[row] + bhh[row];
        }
    }
    __syncthreads();
    if (tid < 16) {
        int t = b * 16 + tid;
        float ig = 1.f / (1.f + expf(-g4[0][tid]));
        float fg = 1.f / (1.f + expf(-g4[1][tid]));
        float gg = tanhf(g4[2][tid]);
        float og = 1.f / (1.f + expf(-g4[3][tid]));
        float c1 = fg * c0[t] + ig * gg;
        float h1 = og * tanhf(c1);
        ws[OFF_H1 + t] = h1; ws[OFF_C1 + t] = c1;
        out[VV + MOOV + t] = h1;
        out[VV + MOOV + 1024 + t] = c1;
    }
}

// K5: fused [big matvec | qc | gen_p], all depend only on h1.
// Blocks 0..NBIG-1: exp(W_out @ h1 + b_out), no LDS, no barrier.
// Blocks NBIG..NBIG+63: qc = W_copy @ h1 + b_copy. Block NBIG+64: gen_p.
__global__ void k_big_qc_genp(const float* __restrict__ W, const float* __restrict__ bias,
                              const float* __restrict__ Wcp, const float* __restrict__ bcp,
                              const float* __restrict__ nameh, const float* __restrict__ typeh,
                              const float* __restrict__ Wg, const float* __restrict__ bg,
                              float* __restrict__ ws) {
    int b = blockIdx.x, tid = threadIdx.x, wave = tid >> 6, lane = tid & 63;
    const float4* h4 = (const float4*)(ws + OFF_H1);
    if (b < NBIG) {
        float4 hv[4] = { h4[lane], h4[lane + 64], h4[lane + 128], h4[lane + 192] };
        int row0 = (b * 4 + wave) * 4;
        float s[4];
        rowsN_dot<4, 4>(W, HH, row0, VV - 1, hv, lane, s);
        float partial = 0.f;
        #pragma unroll
        for (int r = 0; r < 4; ++r) {
            float v = wred(s[r]);
            int row = row0 + r;
            if (lane == 0 && row < VV) {
                float e = __expf(v + bias[row]);
                ws[OFF_LOGIT + row] = e;
                partial += e;
            }
        }
        if (lane == 0) atomicAdd(&ws[OFF_SUMPART + (b & 31) * 32], partial);
    } else if (b < NBIG + 64) {
        int bb = b - NBIG;
        float4 hv[4] = { h4[lane], h4[lane + 64], h4[lane + 128], h4[lane + 192] };
        int row0 = (bb * 4 + wave) * 4;                 // < 1024
        float s[4];
        rowsN_dot<4, 4>(Wcp, HH, row0, 1023, hv, lane, s);
        #pragma unroll
        for (int r = 0; r < 4; ++r) {
            float v = wred(s[r]);
            if (lane == 0) ws[OFF_QC + row0 + r] = v + bcp[row0 + r];
        }
    } else {
        // gen_p = sigmoid(W_gen . [h1, name_h, type_h, x] + b_gen)
        float p = 0.f;
        #pragma unroll
        for (int j = 0; j < 14; ++j) {
            int k = tid + 256 * j;
            float cat = (k < 1024) ? ws[OFF_H1 + k]
                      : (k < 2048) ? nameh[k - 1024]
                      : (k < 3072) ? typeh[k - 2048]
                                   : ws[OFF_X + k - 3072];
            p += Wg[k] * cat;
        }
        __shared__ float red[4];
        float su = wred_all(p);
        if ((tid & 63) == 0) red[tid >> 6] = su;
        __syncthreads();
        if (tid == 0) {
            float ss = red[0] + red[1] + red[2] + red[3];
            ws[OFF_GENP] = 1.f / (1.f + expf(-(ss + bg[0])));
        }
    }
}

// K6: per-s: scores = type_hiddens[s] @ qc, softmax, scale, scatter into pcopy
__global__ void k_attn_scatter(const float* __restrict__ type, const int* __restrict__ idx,
                               float* __restrict__ ws) {
    __shared__ float sc[TSS];
    __shared__ float sh_m, sh_s;
    int s = blockIdx.x, tid = threadIdx.x;
    int wave = tid >> 6, lane = tid & 63;
    const float4* q4 = (const float4*)(ws + OFF_QC);
    float4 qv[4] = { q4[lane], q4[lane + 64], q4[lane + 128], q4[lane + 192] };
    #pragma unroll
    for (int g = 0; g < 8; ++g) {
        int rloc = wave * 32 + g * 4;
        int r0 = s * TSS + rloc;
        float sv[4];
        rowsN_dot<4, 4>(type, HH, r0, 1 << 30, qv, lane, sv);
        #pragma unroll
        for (int r = 0; r < 4; ++r) {
            float v = wred(sv[r]);
            if (lane == 0) sc[rloc + r] = v;
        }
    }
    __syncthreads();
    if (wave == 0) {
        float v0 = sc[lane], v1 = sc[lane + 64];
        float m = wmax_all(fmaxf(v0, v1));
        float su = wred_all(expf(v0 - m) + expf(v1 - m));
        if (lane == 0) { sh_m = m; sh_s = su; }
    }
    __syncthreads();
    if (tid < TSS) {
        float scale = (1.f - ws[OFF_GENP]) * ws[OFF_SIM + s] / sh_s;
        float w = scale * expf(sc[tid] - sh_m);
        atomicAdd(&ws[OFF_PCOPY + idx[s * TSS + tid]], w);
    }
}

// K7: out[v] = log(clip(gen_p * p_vocab[v] + p_copy[v]))
__global__ void k_final(const float* __restrict__ ws, float* __restrict__ out) {
    __shared__ float ssum;
    int tid = threadIdx.x;
    if (tid < 64) {
        float v = (tid < 32) ? ws[OFF_SUMPART + tid * 32] : 0.f;
        v = wred_all(v);
        if (tid == 0) ssum = v;
    }
    __syncthreads();
    int g = blockIdx.x * 256 + tid;
    if (g >= VV + MOOV) return;
    float gp = ws[OFF_GENP];
    float pv = (g < VV) ? ws[OFF_LOGIT + g] / ssum : 0.f;
    float prob = gp * pv + ws[OFF_PCOPY + g];
    out[g] = logf(fmaxf(prob, 1e-10f));
}

extern "C" void kernel_launch(void* const* d_in, const int* in_sizes, int n_in,
                              void* d_out, int out_size, void* d_ws, size_t ws_size,
                              hipStream_t stream) {
    (void)in_sizes; (void)n_in; (void)out_size; (void)ws_size;
    const float* emb   = (const float*)d_in[0];
    const float* h0    = (const float*)d_in[1];
    const float* c0    = (const float*)d_in[2];
    const float* enc   = (const float*)d_in[3];
    const float* name  = (const float*)d_in[4];
    const float* type  = (const float*)d_in[5];
    const float* nameh = (const float*)d_in[6];
    const float* typeh = (const float*)d_in[7];
    const float* Wma   = (const float*)d_in[8];
    const float* bma   = (const float*)d_in[9];
    const float* Wmc   = (const float*)d_in[10];
    const float* bmc   = (const float*)d_in[11];
    const float* Wih   = (const float*)d_in[12];
    const float* Whh   = (const float*)d_in[13];
    const float* bih   = (const float*)d_in[14];
    const float* bhh   = (const float*)d_in[15];
    const float* Wcp   = (const float*)d_in[16];
    const float* bcp   = (const float*)d_in[17];
    const float* Wg    = (const float*)d_in[18];
    const float* bg    = (const float*)d_in[19];
    const float* Wout  = (const float*)d_in[20];
    const float* bout  = (const float*)d_in[21];
    const int*   tidx  = (const int*)d_in[22];
    float* out = (float*)d_out;
    float* ws  = (float*)d_ws;

    k_init_q      <<<197,      256, 0, stream>>>(emb, Wma, bma, ws);
    k_scores_ctx  <<<161,      256, 0, stream>>>(enc, name, type, ws);
    k_x           <<<128,      256, 0, stream>>>(Wmc, bmc, ws);
    k_gates_lstm  <<<64,       256, 0, stream>>>(Wih, Whh, bih, bhh, h0, c0, ws, out);
    k_big_qc_genp <<<NBIG + 65, 256, 0, stream>>>(Wout, bout, Wcp, bcp, nameh, typeh, Wg, bg, ws);
    k_attn_scatter<<<8,        256, 0, stream>>>(type, tidx, ws);
    k_final       <<<197,      256, 0, stream>>>(ws, out);
}